// Round 3
// baseline (1006.687 us; speedup 1.0000x reference)
//
#include <hip/hip_runtime.h>

#define N_NODES 100000
#define N_EDGES 1600000
#define NB 782  // ceil(N_NODES/128) buckets of 128 dst nodes

typedef __attribute__((ext_vector_type(8))) short short8;
typedef __attribute__((ext_vector_type(4))) float float4e;

// async 16B global->LDS copy (lane-contiguous LDS dest)
#define GLDS16(g, l)                                                   \
  __builtin_amdgcn_global_load_lds(                                    \
      (const __attribute__((address_space(1))) unsigned int*)(g),      \
      (__attribute__((address_space(3))) unsigned int*)(l), 16, 0, 0)

// ---------------------------------------------------------------------------
// bf16 split helpers (RNE)
// ---------------------------------------------------------------------------
__device__ __forceinline__ unsigned short f2bf(float f) {
  unsigned u = __float_as_uint(f);
  u += 0x7FFFu + ((u >> 16) & 1u);
  return (unsigned short)(u >> 16);
}
__device__ __forceinline__ float bf2f(unsigned short h) {
  return __uint_as_float(((unsigned)h) << 16);
}

// ===========================================================================
// Bucketed CSR build (scratch in d_out, dead before final GEMM).
//   bucket b = dst >> 7 (128 nodes each). packed edge = (src<<7)|(dst&127).
// ===========================================================================
__global__ __launch_bounds__(256) void bucketHist_k(const int* __restrict__ dst,
                                                    int* __restrict__ bucketCnt,
                                                    int nE) {
  __shared__ int h[1024];
  for (int j = threadIdx.x; j < 1024; j += 256) h[j] = 0;
  __syncthreads();
  const int stride = gridDim.x * 256;
  for (int i = blockIdx.x * 256 + threadIdx.x; i < nE; i += stride)
    atomicAdd(&h[dst[i] >> 7], 1);
  __syncthreads();
  for (int j = threadIdx.x; j < NB; j += 256) {
    int v = h[j];
    if (v) atomicAdd(&bucketCnt[j], v);
  }
}

// single-block exclusive scan of bucket counts -> bucketStart[0..NB], cursor copy
__global__ __launch_bounds__(1024) void scanB_k(const int* __restrict__ bucketCnt,
                                                int* __restrict__ bucketStart,
                                                int* __restrict__ bucketCursor) {
  __shared__ int sm[1024];
  const int tid = threadIdx.x;
  int v = (tid < NB) ? bucketCnt[tid] : 0;
  sm[tid] = v;
  __syncthreads();
  for (int off = 1; off < 1024; off <<= 1) {
    int t = (tid >= off) ? sm[tid - off] : 0;
    __syncthreads();
    sm[tid] += t;
    __syncthreads();
  }
  if (tid < NB) {
    int excl = sm[tid] - v;
    bucketStart[tid] = excl;
    bucketCursor[tid] = excl;
  }
  if (tid == NB - 1) bucketStart[NB] = sm[tid];
}

__global__ __launch_bounds__(256) void bucketScatter_k(
    const int* __restrict__ src, const int* __restrict__ dst,
    int* __restrict__ bucketCursor, unsigned int* __restrict__ packed, int nE) {
  int i = blockIdx.x * 256 + threadIdx.x;
  if (i < nE) {
    int d = dst[i];
    int p = atomicAdd(&bucketCursor[d >> 7], 1);
    packed[p] = ((unsigned)src[i] << 7) | (unsigned)(d & 127);
  }
}

// one block per bucket: LDS node-count + local scan -> rowEnd; LDS-cursor
// scatter of sortedSrc confined to this bucket's contiguous CSR range.
__global__ __launch_bounds__(256) void fillB_k(
    const int* __restrict__ bucketStart, const unsigned int* __restrict__ packed,
    int* __restrict__ rowEnd, int* __restrict__ sortedSrc, int nNodes) {
  __shared__ int cnt[128];
  __shared__ int cur[128];
  const int b = blockIdx.x;
  const int tid = threadIdx.x;
  const int s0 = bucketStart[b];
  const int ne = bucketStart[b + 1] - s0;
  if (tid < 128) cnt[tid] = 0;
  __syncthreads();
  for (int i = tid; i < ne; i += 256)
    atomicAdd(&cnt[packed[s0 + i] & 127u], 1);
  __syncthreads();
  int v = (tid < 128) ? cnt[tid] : 0;
  // Hillis-Steele inclusive scan over 128 (all threads hit both barriers)
  for (int off = 1; off < 128; off <<= 1) {
    int t = (tid < 128 && tid >= off) ? cnt[tid - off] : 0;
    __syncthreads();
    if (tid < 128) cnt[tid] += t;
    __syncthreads();
  }
  if (tid < 128) {
    cur[tid] = s0 + cnt[tid] - v;  // exclusive start for this node
    int node = b * 128 + tid;
    if (node < nNodes) rowEnd[node] = s0 + cnt[tid];
  }
  __syncthreads();
  for (int i = tid; i < ne; i += 256) {
    unsigned p = packed[s0 + i];
    int idx = atomicAdd(&cur[p & 127u], 1);
    sortedSrc[idx] = (int)(p >> 7);
  }
}

// ===========================================================================
// Weight prep: W[K][N] fp32 -> transposed bf16 hi/lo planes [N][K].
// ===========================================================================
__global__ __launch_bounds__(256) void wprep_k(
    const float* __restrict__ W, unsigned short* __restrict__ th,
    unsigned short* __restrict__ tl, int K, int N) {
  int i = blockIdx.x * blockDim.x + threadIdx.x;
  if (i < K * N) {
    int k = i / N, n = i % N;
    float v = W[i];
    unsigned short h = f2bf(v);
    unsigned short l = f2bf(v - bf2f(h));
    th[(long)n * K + k] = h;
    tl[(long)n * K + k] = l;
  }
}

// x fp32 -> bf16 hi plane (for the gather path)
__global__ __launch_bounds__(256) void xprep_k(const float* __restrict__ x,
                                               unsigned short* __restrict__ xh,
                                               int n) {
  int i = blockIdx.x * blockDim.x + threadIdx.x;
  if (i < n) xh[i] = f2bf(x[i]);
}

// ===========================================================================
// CSR gather-sum (bf16 rows) + GIN combine -> bf16 hi/lo planes.
//   res = (1+eps)*self[n] + sum_{in-edges} bf2f(feat_h[src])
//   XF32: self from fp32 xf; else self = bf2f(xh)+bf2f(xl) (hi/lo planes).
// One wave per node; lane holds C/64 channels (ushort2/ushort4 gathers).
// Inner loop: 8 independent row-gathers in flight per round (latency hiding).
// ===========================================================================
template <int C, bool XF32>
__global__ __launch_bounds__(256) void agg_g16_k(
    const unsigned short* __restrict__ feat_h, const float* __restrict__ xf,
    const unsigned short* __restrict__ xh, const unsigned short* __restrict__ xl,
    const float* __restrict__ epsp, const int* __restrict__ rowEnd,
    const int* __restrict__ sortedSrc, unsigned short* __restrict__ oh,
    unsigned short* __restrict__ ol, int M) {
  constexpr int V = C / 64;
  const int lane = threadIdx.x & 63;
  const int w = (int)((blockIdx.x * blockDim.x + threadIdx.x) >> 6);
  if (w >= M) return;
  const int start = w ? rowEnd[w - 1] : 0;
  const int end = rowEnd[w];
  const int c0 = lane * V;

  float acc[V] = {};
  int e = start;
  // 8-deep gather window: issue all 8 loads before consuming any.
  for (; e + 8 <= end; e += 8) {
    int si[8];
#pragma unroll
    for (int q = 0; q < 8; ++q) si[q] = sortedSrc[e + q];
    if constexpr (V == 4) {
      ushort4 t[8];
#pragma unroll
      for (int q = 0; q < 8; ++q)
        t[q] = *(const ushort4*)(feat_h + (long)si[q] * C + c0);
#pragma unroll
      for (int q = 0; q < 8; ++q) {
        acc[0] += bf2f(t[q].x);
        acc[1] += bf2f(t[q].y);
        acc[2] += bf2f(t[q].z);
        acc[3] += bf2f(t[q].w);
      }
    } else {
      ushort2 t[8];
#pragma unroll
      for (int q = 0; q < 8; ++q)
        t[q] = *(const ushort2*)(feat_h + (long)si[q] * C + c0);
#pragma unroll
      for (int q = 0; q < 8; ++q) {
        acc[0] += bf2f(t[q].x);
        acc[1] += bf2f(t[q].y);
      }
    }
  }
  for (; e + 4 <= end; e += 4) {
    int s0 = sortedSrc[e + 0];
    int s1 = sortedSrc[e + 1];
    int s2 = sortedSrc[e + 2];
    int s3 = sortedSrc[e + 3];
    if constexpr (V == 4) {
      ushort4 a = *(const ushort4*)(feat_h + (long)s0 * C + c0);
      ushort4 b = *(const ushort4*)(feat_h + (long)s1 * C + c0);
      ushort4 c = *(const ushort4*)(feat_h + (long)s2 * C + c0);
      ushort4 d = *(const ushort4*)(feat_h + (long)s3 * C + c0);
      acc[0] += bf2f(a.x) + bf2f(b.x) + bf2f(c.x) + bf2f(d.x);
      acc[1] += bf2f(a.y) + bf2f(b.y) + bf2f(c.y) + bf2f(d.y);
      acc[2] += bf2f(a.z) + bf2f(b.z) + bf2f(c.z) + bf2f(d.z);
      acc[3] += bf2f(a.w) + bf2f(b.w) + bf2f(c.w) + bf2f(d.w);
    } else {
      ushort2 a = *(const ushort2*)(feat_h + (long)s0 * C + c0);
      ushort2 b = *(const ushort2*)(feat_h + (long)s1 * C + c0);
      ushort2 c = *(const ushort2*)(feat_h + (long)s2 * C + c0);
      ushort2 d = *(const ushort2*)(feat_h + (long)s3 * C + c0);
      acc[0] += bf2f(a.x) + bf2f(b.x) + bf2f(c.x) + bf2f(d.x);
      acc[1] += bf2f(a.y) + bf2f(b.y) + bf2f(c.y) + bf2f(d.y);
    }
  }
  for (; e < end; ++e) {
    const unsigned short* r = feat_h + (long)sortedSrc[e] * C + c0;
    if constexpr (V == 4) {
      ushort4 a = *(const ushort4*)r;
      acc[0] += bf2f(a.x); acc[1] += bf2f(a.y);
      acc[2] += bf2f(a.z); acc[3] += bf2f(a.w);
    } else {
      ushort2 a = *(const ushort2*)r;
      acc[0] += bf2f(a.x); acc[1] += bf2f(a.y);
    }
  }

  const float s = 1.0f + epsp[0];
  float xv[V];
  if constexpr (XF32) {
#pragma unroll
    for (int v = 0; v < V; ++v) xv[v] = xf[(long)w * C + c0 + v];
  } else {
#pragma unroll
    for (int v = 0; v < V; ++v)
      xv[v] = bf2f(xh[(long)w * C + c0 + v]) + bf2f(xl[(long)w * C + c0 + v]);
  }

  unsigned short hv[V], lv[V];
#pragma unroll
  for (int v = 0; v < V; ++v) {
    float res = fmaf(s, xv[v], acc[v]);
    hv[v] = f2bf(res);
    lv[v] = f2bf(res - bf2f(hv[v]));
  }
  if constexpr (V == 4) {
    *(ushort4*)&oh[(long)w * C + c0] = make_ushort4(hv[0], hv[1], hv[2], hv[3]);
    *(ushort4*)&ol[(long)w * C + c0] = make_ushort4(lv[0], lv[1], lv[2], lv[3]);
  } else {
    *(ushort2*)&oh[(long)w * C + c0] = make_ushort2(hv[0], hv[1]);
    *(ushort2*)&ol[(long)w * C + c0] = make_ushort2(lv[0], lv[1]);
  }
}

// ===========================================================================
// Split-bf16 MFMA GEMM, full-N blocks: A staged ONCE from global.
//   Block = 64 rows x N (N = NFRAG*16). 4 waves; wave = 16-row m-frag x NFRAG.
//   Per K-iter (BK=32): stage A 64x32 hilo (HBM) + B Nx32 hilo (L2) via
//   global_load_lds w16; 3-pass split MFMA (hh, hl, lh).
// ===========================================================================
template <int NFRAG, bool RELU, bool HILO>
__global__ __launch_bounds__(256, 3) void gemm_wide_k(
    const unsigned short* __restrict__ Ah, const unsigned short* __restrict__ Al,
    const unsigned short* __restrict__ Bth, const unsigned short* __restrict__ Btl,
    const float* __restrict__ bias, float* __restrict__ outf,
    unsigned short* __restrict__ oh, unsigned short* __restrict__ ol,
    int M, int K) {
  constexpr int N = NFRAG * 16;
  __shared__ unsigned short Ahs[64 * 32];
  __shared__ unsigned short Als[64 * 32];
  __shared__ unsigned short Bhs[N * 32];
  __shared__ unsigned short Bls[N * 32];

  const int tid = threadIdx.x;
  const int lane = tid & 63;
  const int wave = tid >> 6;
  const int l15 = lane & 15;
  const int quad = lane >> 4;
  const int m0 = blockIdx.x * 64;

  float4e acc[NFRAG];
#pragma unroll
  for (int j = 0; j < NFRAG; ++j) acc[j] = 0.0f;

  const int a_row = tid >> 2;
  const int a_col = (tid & 3) * 8;
  const bool a_ok = (m0 + a_row) < M;

  for (int k0 = 0; k0 < K; k0 += 32) {
    {
      long ga = (long)(m0 + a_row) * K + k0 + a_col;
      if (a_ok) {
        GLDS16(Ah + ga, &Ahs[tid * 8]);
        GLDS16(Al + ga, &Als[tid * 8]);
      }
    }
#pragma unroll
    for (int u = 0; u < NFRAG / 4; ++u) {
      int c = u * 256 + tid;
      long gb = (long)(c >> 2) * K + k0 + (c & 3) * 8;
      GLDS16(Bth + gb, &Bhs[c * 8]);
      GLDS16(Btl + gb, &Bls[c * 8]);
    }
    __syncthreads();

    short8 a_h = *(const short8*)&Ahs[(wave * 16 + l15) * 32 + quad * 8];
    short8 a_l = *(const short8*)&Als[(wave * 16 + l15) * 32 + quad * 8];

#pragma unroll
    for (int j = 0; j < NFRAG; ++j) {
      short8 b_h = *(const short8*)&Bhs[(j * 16 + l15) * 32 + quad * 8];
      short8 b_l = *(const short8*)&Bls[(j * 16 + l15) * 32 + quad * 8];
      acc[j] = __builtin_amdgcn_mfma_f32_16x16x32_bf16(a_h, b_h, acc[j], 0, 0, 0);
      acc[j] = __builtin_amdgcn_mfma_f32_16x16x32_bf16(a_h, b_l, acc[j], 0, 0, 0);
      acc[j] = __builtin_amdgcn_mfma_f32_16x16x32_bf16(a_l, b_h, acc[j], 0, 0, 0);
    }
    __syncthreads();
  }

#pragma unroll
  for (int j = 0; j < NFRAG; ++j) {
    int col = j * 16 + l15;
    float bj = bias[col];
    int rbase = m0 + wave * 16 + quad * 4;
#pragma unroll
    for (int r = 0; r < 4; ++r) {
      int row = rbase + r;
      if (row < M) {
        float v = acc[j][r] + bj;
        if constexpr (RELU) v = fmaxf(v, 0.0f);
        if constexpr (HILO) {
          unsigned short h = f2bf(v);
          oh[(long)row * N + col] = h;
          ol[(long)row * N + col] = f2bf(v - bf2f(h));
        } else {
          outf[(long)row * N + col] = v;
        }
      }
    }
  }
}

extern "C" void kernel_launch(void* const* d_in, const int* in_sizes, int n_in,
                              void* d_out, int out_size, void* d_ws, size_t ws_size,
                              hipStream_t stream) {
  const float* x    = (const float*)d_in[0];
  const int*   ei   = (const int*)d_in[1];
  const float* eps1 = (const float*)d_in[2];
  const float* W1a  = (const float*)d_in[3];
  const float* b1a  = (const float*)d_in[4];
  const float* W1b  = (const float*)d_in[5];
  const float* b1b  = (const float*)d_in[6];
  const float* eps2 = (const float*)d_in[7];
  const float* W2a  = (const float*)d_in[8];
  const float* b2a  = (const float*)d_in[9];
  const float* W2b  = (const float*)d_in[10];
  const float* b2b  = (const float*)d_in[11];
  float* out = (float*)d_out;

  const int* srcp = ei;
  const int* dstp = ei + N_EDGES;

  // ---- workspace: two 102.4MB halves, cycled ----
  char* ws = (char*)d_ws;
  const size_t SZ = (size_t)N_NODES * 256 * sizeof(float);  // 102.4 MB
  char* P1 = ws;
  char* P2 = ws + SZ;

  // P1 phase A: C1 hilo [M][128] (51.2MB) + xh [M][128] bf16 (25.6MB)
  unsigned short* C1h = (unsigned short*)P1;
  unsigned short* C1l = C1h + (size_t)N_NODES * 128;
  unsigned short* xh  = C1l + (size_t)N_NODES * 128;
  // P2 phase A: T1 hilo [M][256] (102.4MB)
  unsigned short* T1h = (unsigned short*)P2;
  unsigned short* T1l = T1h + (size_t)N_NODES * 256;
  // P1 phase B: H hilo [M][256] (102.4MB)  (C1/xh dead)
  unsigned short* Hh = (unsigned short*)P1;
  unsigned short* Hl = Hh + (size_t)N_NODES * 256;
  // P2 phase B: C2 hilo [M][256]  (T1 dead)
  unsigned short* C2h = (unsigned short*)P2;
  unsigned short* C2l = C2h + (size_t)N_NODES * 256;
  // P1 phase C: T2 hilo [M][256]  (H dead)
  unsigned short* T2h = (unsigned short*)P1;
  unsigned short* T2l = T2h + (size_t)N_NODES * 256;
  // P2 phase C: W2b planes (C2 dead)
  unsigned short* W2bh = (unsigned short*)P2;
  unsigned short* W2bl = W2bh + 128 * 256;

  // ---- d_out scratch: CSR + early weight planes (dead before final GEMM) ----
  char* ob = (char*)d_out;
  int* rowEnd    = (int*)(ob + 400 * 1024);
  int* sortedSrc = (int*)(ob + 800 * 1024);
  // bucket arrays in the gap below the weight planes
  int* bucketCnt    = (int*)(ob + 7219200);            // 1024 ints
  int* bucketStart  = (int*)(ob + 7219200 + 4096);     // NB+1 ints
  int* bucketCursor = (int*)(ob + 7219200 + 4096 + 4096);  // NB ints
  unsigned int* packed = (unsigned int*)(ob + 16 * 1024 * 1024);  // 6.4MB
  size_t wofs = 7340032;
  unsigned short* W1ah = (unsigned short*)(ob + wofs);
  unsigned short* W1al = W1ah + 256 * 128;
  unsigned short* W1bh = (unsigned short*)(ob + wofs + 2 * 65536);
  unsigned short* W1bl = W1bh + 256 * 256;
  unsigned short* W2ah = (unsigned short*)(ob + wofs + 2 * 65536 + 2 * 131072);
  unsigned short* W2al = W2ah + 256 * 256;

  dim3 blk(256);
  dim3 gEdges((N_EDGES + 255) / 256);
  dim3 gAgg((N_NODES + 3) / 4);
  dim3 gGemm((N_NODES + 63) / 64);
  dim3 gW1((128 * 256 + 255) / 256);
  dim3 gW2((256 * 256 + 255) / 256);
  dim3 gXp((N_NODES * 128 + 255) / 256);

  // ---- bucketed CSR build + weight/x prep ----
  hipMemsetAsync(bucketCnt, 0, 1024 * sizeof(int), stream);
  bucketHist_k<<<dim3(512), blk, 0, stream>>>(dstp, bucketCnt, N_EDGES);
  scanB_k<<<1, dim3(1024), 0, stream>>>(bucketCnt, bucketStart, bucketCursor);
  bucketScatter_k<<<gEdges, blk, 0, stream>>>(srcp, dstp, bucketCursor, packed,
                                              N_EDGES);
  fillB_k<<<dim3(NB), blk, 0, stream>>>(bucketStart, packed, rowEnd, sortedSrc,
                                        N_NODES);
  xprep_k<<<gXp, blk, 0, stream>>>(x, xh, N_NODES * 128);
  wprep_k<<<gW1, blk, 0, stream>>>(W1a, W1ah, W1al, 128, 256);
  wprep_k<<<gW2, blk, 0, stream>>>(W1b, W1bh, W1bl, 256, 256);
  wprep_k<<<gW2, blk, 0, stream>>>(W2a, W2ah, W2al, 256, 256);

  // ---- Layer 1 ----
  agg_g16_k<128, true><<<gAgg, blk, 0, stream>>>(
      xh, x, nullptr, nullptr, eps1, rowEnd, sortedSrc, C1h, C1l, N_NODES);
  gemm_wide_k<16, true, true><<<gGemm, blk, 0, stream>>>(
      C1h, C1l, W1ah, W1al, b1a, nullptr, T1h, T1l, N_NODES, 128);
  gemm_wide_k<16, true, true><<<gGemm, blk, 0, stream>>>(
      T1h, T1l, W1bh, W1bl, b1b, nullptr, Hh, Hl, N_NODES, 256);  // h as hilo

  // ---- Layer 2 ----
  agg_g16_k<256, false><<<gAgg, blk, 0, stream>>>(
      Hh, nullptr, Hh, Hl, eps2, rowEnd, sortedSrc, C2h, C2l, N_NODES);
  gemm_wide_k<16, true, true><<<gGemm, blk, 0, stream>>>(
      C2h, C2l, W2ah, W2al, b2a, nullptr, T2h, T2l, N_NODES, 256);
  wprep_k<<<gW1, blk, 0, stream>>>(W2b, W2bh, W2bl, 256, 128);  // C2 dead now
  gemm_wide_k<8, false, false><<<gGemm, blk, 0, stream>>>(
      T2h, T2l, W2bh, W2bl, b2b, out, nullptr, nullptr, N_NODES, 256);
}

// Round 4
// 753.457 us; speedup vs baseline: 1.3361x; 1.3361x over previous
//
#include <hip/hip_runtime.h>

#define N_NODES 100000
#define N_EDGES 1600000
#define NB 782      // ceil(N_NODES/128) buckets of 128 dst nodes
#define BSTRIDE 32  // ints per atomic counter slot (128 B) -- kills false sharing

typedef __attribute__((ext_vector_type(8))) short short8;
typedef __attribute__((ext_vector_type(4))) float float4e;

// async 16B global->LDS copy (lane-contiguous LDS dest)
#define GLDS16(g, l)                                                   \
  __builtin_amdgcn_global_load_lds(                                    \
      (const __attribute__((address_space(1))) unsigned int*)(g),      \
      (__attribute__((address_space(3))) unsigned int*)(l), 16, 0, 0)

// ---------------------------------------------------------------------------
// bf16 split helpers (RNE)
// ---------------------------------------------------------------------------
__device__ __forceinline__ unsigned short f2bf(float f) {
  unsigned u = __float_as_uint(f);
  u += 0x7FFFu + ((u >> 16) & 1u);
  return (unsigned short)(u >> 16);
}
__device__ __forceinline__ float bf2f(unsigned short h) {
  return __uint_as_float(((unsigned)h) << 16);
}

// ===========================================================================
// Bucketed CSR build (scratch in d_out, dead before final GEMM).
//   bucket b = dst >> 7 (128 nodes each). packed edge = (src<<7)|(dst&127).
//   All global atomic counters padded to 1 per 128B line (BSTRIDE).
// ===========================================================================
__global__ __launch_bounds__(256) void bucketHist_k(const int* __restrict__ dst,
                                                    int* __restrict__ bucketCnt,
                                                    int nE) {
  __shared__ int h[1024];
  for (int j = threadIdx.x; j < 1024; j += 256) h[j] = 0;
  __syncthreads();
  const int stride = gridDim.x * 256;
  for (int i = blockIdx.x * 256 + threadIdx.x; i < nE; i += stride)
    atomicAdd(&h[dst[i] >> 7], 1);
  __syncthreads();
  for (int j = threadIdx.x; j < NB; j += 256) {
    int v = h[j];
    if (v) atomicAdd(&bucketCnt[j * BSTRIDE], v);
  }
}

// single-block exclusive scan of bucket counts -> bucketStart[0..NB], cursor copy
__global__ __launch_bounds__(1024) void scanB_k(const int* __restrict__ bucketCnt,
                                                int* __restrict__ bucketStart,
                                                int* __restrict__ bucketCursor) {
  __shared__ int sm[1024];
  const int tid = threadIdx.x;
  int v = (tid < NB) ? bucketCnt[tid * BSTRIDE] : 0;
  sm[tid] = v;
  __syncthreads();
  for (int off = 1; off < 1024; off <<= 1) {
    int t = (tid >= off) ? sm[tid - off] : 0;
    __syncthreads();
    sm[tid] += t;
    __syncthreads();
  }
  if (tid < NB) {
    int excl = sm[tid] - v;
    bucketStart[tid] = excl;
    bucketCursor[tid * BSTRIDE] = excl;
  }
  if (tid == NB - 1) bucketStart[NB] = sm[tid];
}

__global__ __launch_bounds__(256) void bucketScatter_k(
    const int* __restrict__ src, const int* __restrict__ dst,
    int* __restrict__ bucketCursor, unsigned int* __restrict__ packed, int nE) {
  int i = blockIdx.x * 256 + threadIdx.x;
  if (i < nE) {
    int d = dst[i];
    int p = atomicAdd(&bucketCursor[(d >> 7) * BSTRIDE], 1);
    packed[p] = ((unsigned)src[i] << 7) | (unsigned)(d & 127);
  }
}

// one block per bucket: LDS node-count + local scan -> rowEnd; LDS-cursor
// scatter of sortedSrc confined to this bucket's contiguous CSR range.
__global__ __launch_bounds__(256) void fillB_k(
    const int* __restrict__ bucketStart, const unsigned int* __restrict__ packed,
    int* __restrict__ rowEnd, int* __restrict__ sortedSrc, int nNodes) {
  __shared__ int cnt[128];
  __shared__ int cur[128];
  const int b = blockIdx.x;
  const int tid = threadIdx.x;
  const int s0 = bucketStart[b];
  const int ne = bucketStart[b + 1] - s0;
  if (tid < 128) cnt[tid] = 0;
  __syncthreads();
  for (int i = tid; i < ne; i += 256)
    atomicAdd(&cnt[packed[s0 + i] & 127u], 1);
  __syncthreads();
  int v = (tid < 128) ? cnt[tid] : 0;
  // Hillis-Steele inclusive scan over 128 (all threads hit both barriers)
  for (int off = 1; off < 128; off <<= 1) {
    int t = (tid < 128 && tid >= off) ? cnt[tid - off] : 0;
    __syncthreads();
    if (tid < 128) cnt[tid] += t;
    __syncthreads();
  }
  if (tid < 128) {
    cur[tid] = s0 + cnt[tid] - v;  // exclusive start for this node
    int node = b * 128 + tid;
    if (node < nNodes) rowEnd[node] = s0 + cnt[tid];
  }
  __syncthreads();
  for (int i = tid; i < ne; i += 256) {
    unsigned p = packed[s0 + i];
    int idx = atomicAdd(&cur[p & 127u], 1);
    sortedSrc[idx] = (int)(p >> 7);
  }
}

// ===========================================================================
// Weight prep: W[K][N] fp32 -> transposed bf16 hi/lo planes [N][K].
// ===========================================================================
__global__ __launch_bounds__(256) void wprep_k(
    const float* __restrict__ W, unsigned short* __restrict__ th,
    unsigned short* __restrict__ tl, int K, int N) {
  int i = blockIdx.x * blockDim.x + threadIdx.x;
  if (i < K * N) {
    int k = i / N, n = i % N;
    float v = W[i];
    unsigned short h = f2bf(v);
    unsigned short l = f2bf(v - bf2f(h));
    th[(long)n * K + k] = h;
    tl[(long)n * K + k] = l;
  }
}

// x fp32 -> bf16 hi plane (for the gather path)
__global__ __launch_bounds__(256) void xprep_k(const float* __restrict__ x,
                                               unsigned short* __restrict__ xh,
                                               int n) {
  int i = blockIdx.x * blockDim.x + threadIdx.x;
  if (i < n) xh[i] = f2bf(x[i]);
}

// ===========================================================================
// CSR gather-sum (bf16 rows) + GIN combine -> bf16 hi/lo planes.
//   res = (1+eps)*self[n] + sum_{in-edges} bf2f(feat_h[src])
//   XF32: self from fp32 xf; else self = bf2f(xh)+bf2f(xl) (hi/lo planes).
// One wave per node; lane holds C/64 channels (ushort2/ushort4 gathers).
// Inner loop: 8 independent row-gathers in flight per round (latency hiding).
// ===========================================================================
template <int C, bool XF32>
__global__ __launch_bounds__(256) void agg_g16_k(
    const unsigned short* __restrict__ feat_h, const float* __restrict__ xf,
    const unsigned short* __restrict__ xh, const unsigned short* __restrict__ xl,
    const float* __restrict__ epsp, const int* __restrict__ rowEnd,
    const int* __restrict__ sortedSrc, unsigned short* __restrict__ oh,
    unsigned short* __restrict__ ol, int M) {
  constexpr int V = C / 64;
  const int lane = threadIdx.x & 63;
  const int w = (int)((blockIdx.x * blockDim.x + threadIdx.x) >> 6);
  if (w >= M) return;
  const int start = w ? rowEnd[w - 1] : 0;
  const int end = rowEnd[w];
  const int c0 = lane * V;

  float acc[V] = {};
  int e = start;
  // 8-deep gather window: issue all 8 loads before consuming any.
  for (; e + 8 <= end; e += 8) {
    int si[8];
#pragma unroll
    for (int q = 0; q < 8; ++q) si[q] = sortedSrc[e + q];
    if constexpr (V == 4) {
      ushort4 t[8];
#pragma unroll
      for (int q = 0; q < 8; ++q)
        t[q] = *(const ushort4*)(feat_h + (long)si[q] * C + c0);
#pragma unroll
      for (int q = 0; q < 8; ++q) {
        acc[0] += bf2f(t[q].x);
        acc[1] += bf2f(t[q].y);
        acc[2] += bf2f(t[q].z);
        acc[3] += bf2f(t[q].w);
      }
    } else {
      ushort2 t[8];
#pragma unroll
      for (int q = 0; q < 8; ++q)
        t[q] = *(const ushort2*)(feat_h + (long)si[q] * C + c0);
#pragma unroll
      for (int q = 0; q < 8; ++q) {
        acc[0] += bf2f(t[q].x);
        acc[1] += bf2f(t[q].y);
      }
    }
  }
  for (; e + 4 <= end; e += 4) {
    int s0 = sortedSrc[e + 0];
    int s1 = sortedSrc[e + 1];
    int s2 = sortedSrc[e + 2];
    int s3 = sortedSrc[e + 3];
    if constexpr (V == 4) {
      ushort4 a = *(const ushort4*)(feat_h + (long)s0 * C + c0);
      ushort4 b = *(const ushort4*)(feat_h + (long)s1 * C + c0);
      ushort4 c = *(const ushort4*)(feat_h + (long)s2 * C + c0);
      ushort4 d = *(const ushort4*)(feat_h + (long)s3 * C + c0);
      acc[0] += bf2f(a.x) + bf2f(b.x) + bf2f(c.x) + bf2f(d.x);
      acc[1] += bf2f(a.y) + bf2f(b.y) + bf2f(c.y) + bf2f(d.y);
      acc[2] += bf2f(a.z) + bf2f(b.z) + bf2f(c.z) + bf2f(d.z);
      acc[3] += bf2f(a.w) + bf2f(b.w) + bf2f(c.w) + bf2f(d.w);
    } else {
      ushort2 a = *(const ushort2*)(feat_h + (long)s0 * C + c0);
      ushort2 b = *(const ushort2*)(feat_h + (long)s1 * C + c0);
      ushort2 c = *(const ushort2*)(feat_h + (long)s2 * C + c0);
      ushort2 d = *(const ushort2*)(feat_h + (long)s3 * C + c0);
      acc[0] += bf2f(a.x) + bf2f(b.x) + bf2f(c.x) + bf2f(d.x);
      acc[1] += bf2f(a.y) + bf2f(b.y) + bf2f(c.y) + bf2f(d.y);
    }
  }
  for (; e < end; ++e) {
    const unsigned short* r = feat_h + (long)sortedSrc[e] * C + c0;
    if constexpr (V == 4) {
      ushort4 a = *(const ushort4*)r;
      acc[0] += bf2f(a.x); acc[1] += bf2f(a.y);
      acc[2] += bf2f(a.z); acc[3] += bf2f(a.w);
    } else {
      ushort2 a = *(const ushort2*)r;
      acc[0] += bf2f(a.x); acc[1] += bf2f(a.y);
    }
  }

  const float s = 1.0f + epsp[0];
  float xv[V];
  if constexpr (XF32) {
#pragma unroll
    for (int v = 0; v < V; ++v) xv[v] = xf[(long)w * C + c0 + v];
  } else {
#pragma unroll
    for (int v = 0; v < V; ++v)
      xv[v] = bf2f(xh[(long)w * C + c0 + v]) + bf2f(xl[(long)w * C + c0 + v]);
  }

  unsigned short hv[V], lv[V];
#pragma unroll
  for (int v = 0; v < V; ++v) {
    float res = fmaf(s, xv[v], acc[v]);
    hv[v] = f2bf(res);
    lv[v] = f2bf(res - bf2f(hv[v]));
  }
  if constexpr (V == 4) {
    *(ushort4*)&oh[(long)w * C + c0] = make_ushort4(hv[0], hv[1], hv[2], hv[3]);
    *(ushort4*)&ol[(long)w * C + c0] = make_ushort4(lv[0], lv[1], lv[2], lv[3]);
  } else {
    *(ushort2*)&oh[(long)w * C + c0] = make_ushort2(hv[0], hv[1]);
    *(ushort2*)&ol[(long)w * C + c0] = make_ushort2(lv[0], lv[1]);
  }
}

// ===========================================================================
// Split-bf16 MFMA GEMM, full-N blocks: A staged ONCE from global.
//   Block = 64 rows x N (N = NFRAG*16). 4 waves; wave = 16-row m-frag x NFRAG.
//   Per K-iter (BK=32): stage A 64x32 hilo (HBM) + B Nx32 hilo (L2) via
//   global_load_lds w16; 3-pass split MFMA (hh, hl, lh).
// ===========================================================================
template <int NFRAG, bool RELU, bool HILO>
__global__ __launch_bounds__(256, 3) void gemm_wide_k(
    const unsigned short* __restrict__ Ah, const unsigned short* __restrict__ Al,
    const unsigned short* __restrict__ Bth, const unsigned short* __restrict__ Btl,
    const float* __restrict__ bias, float* __restrict__ outf,
    unsigned short* __restrict__ oh, unsigned short* __restrict__ ol,
    int M, int K) {
  constexpr int N = NFRAG * 16;
  __shared__ unsigned short Ahs[64 * 32];
  __shared__ unsigned short Als[64 * 32];
  __shared__ unsigned short Bhs[N * 32];
  __shared__ unsigned short Bls[N * 32];

  const int tid = threadIdx.x;
  const int lane = tid & 63;
  const int wave = tid >> 6;
  const int l15 = lane & 15;
  const int quad = lane >> 4;
  const int m0 = blockIdx.x * 64;

  float4e acc[NFRAG];
#pragma unroll
  for (int j = 0; j < NFRAG; ++j) acc[j] = 0.0f;

  const int a_row = tid >> 2;
  const int a_col = (tid & 3) * 8;
  const bool a_ok = (m0 + a_row) < M;

  for (int k0 = 0; k0 < K; k0 += 32) {
    {
      long ga = (long)(m0 + a_row) * K + k0 + a_col;
      if (a_ok) {
        GLDS16(Ah + ga, &Ahs[tid * 8]);
        GLDS16(Al + ga, &Als[tid * 8]);
      }
    }
#pragma unroll
    for (int u = 0; u < NFRAG / 4; ++u) {
      int c = u * 256 + tid;
      long gb = (long)(c >> 2) * K + k0 + (c & 3) * 8;
      GLDS16(Bth + gb, &Bhs[c * 8]);
      GLDS16(Btl + gb, &Bls[c * 8]);
    }
    __syncthreads();

    short8 a_h = *(const short8*)&Ahs[(wave * 16 + l15) * 32 + quad * 8];
    short8 a_l = *(const short8*)&Als[(wave * 16 + l15) * 32 + quad * 8];

#pragma unroll
    for (int j = 0; j < NFRAG; ++j) {
      short8 b_h = *(const short8*)&Bhs[(j * 16 + l15) * 32 + quad * 8];
      short8 b_l = *(const short8*)&Bls[(j * 16 + l15) * 32 + quad * 8];
      acc[j] = __builtin_amdgcn_mfma_f32_16x16x32_bf16(a_h, b_h, acc[j], 0, 0, 0);
      acc[j] = __builtin_amdgcn_mfma_f32_16x16x32_bf16(a_h, b_l, acc[j], 0, 0, 0);
      acc[j] = __builtin_amdgcn_mfma_f32_16x16x32_bf16(a_l, b_h, acc[j], 0, 0, 0);
    }
    __syncthreads();
  }

#pragma unroll
  for (int j = 0; j < NFRAG; ++j) {
    int col = j * 16 + l15;
    float bj = bias[col];
    int rbase = m0 + wave * 16 + quad * 4;
#pragma unroll
    for (int r = 0; r < 4; ++r) {
      int row = rbase + r;
      if (row < M) {
        float v = acc[j][r] + bj;
        if constexpr (RELU) v = fmaxf(v, 0.0f);
        if constexpr (HILO) {
          unsigned short h = f2bf(v);
          oh[(long)row * N + col] = h;
          ol[(long)row * N + col] = f2bf(v - bf2f(h));
        } else {
          outf[(long)row * N + col] = v;
        }
      }
    }
  }
}

extern "C" void kernel_launch(void* const* d_in, const int* in_sizes, int n_in,
                              void* d_out, int out_size, void* d_ws, size_t ws_size,
                              hipStream_t stream) {
  const float* x    = (const float*)d_in[0];
  const int*   ei   = (const int*)d_in[1];
  const float* eps1 = (const float*)d_in[2];
  const float* W1a  = (const float*)d_in[3];
  const float* b1a  = (const float*)d_in[4];
  const float* W1b  = (const float*)d_in[5];
  const float* b1b  = (const float*)d_in[6];
  const float* eps2 = (const float*)d_in[7];
  const float* W2a  = (const float*)d_in[8];
  const float* b2a  = (const float*)d_in[9];
  const float* W2b  = (const float*)d_in[10];
  const float* b2b  = (const float*)d_in[11];
  float* out = (float*)d_out;

  const int* srcp = ei;
  const int* dstp = ei + N_EDGES;

  // ---- workspace: two 102.4MB halves, cycled ----
  char* ws = (char*)d_ws;
  const size_t SZ = (size_t)N_NODES * 256 * sizeof(float);  // 102.4 MB
  char* P1 = ws;
  char* P2 = ws + SZ;

  // P1 phase A: C1 hilo [M][128] (51.2MB) + xh [M][128] bf16 (25.6MB)
  unsigned short* C1h = (unsigned short*)P1;
  unsigned short* C1l = C1h + (size_t)N_NODES * 128;
  unsigned short* xh  = C1l + (size_t)N_NODES * 128;
  // P2 phase A: T1 hilo [M][256] (102.4MB)
  unsigned short* T1h = (unsigned short*)P2;
  unsigned short* T1l = T1h + (size_t)N_NODES * 256;
  // P1 phase B: H hilo [M][256] (102.4MB)  (C1/xh dead)
  unsigned short* Hh = (unsigned short*)P1;
  unsigned short* Hl = Hh + (size_t)N_NODES * 256;
  // P2 phase B: C2 hilo [M][256]  (T1 dead)
  unsigned short* C2h = (unsigned short*)P2;
  unsigned short* C2l = C2h + (size_t)N_NODES * 256;
  // P1 phase C: T2 hilo [M][256]  (H dead)
  unsigned short* T2h = (unsigned short*)P1;
  unsigned short* T2l = T2h + (size_t)N_NODES * 256;
  // P2 phase C: W2b planes (C2 dead)
  unsigned short* W2bh = (unsigned short*)P2;
  unsigned short* W2bl = W2bh + 128 * 256;

  // ---- d_out scratch: CSR + early weight planes (dead before final GEMM) ----
  char* ob = (char*)d_out;
  int* rowEnd    = (int*)(ob + 400 * 1024);
  int* sortedSrc = (int*)(ob + 800 * 1024);
  size_t wofs = 7340032;
  unsigned short* W1ah = (unsigned short*)(ob + wofs);
  unsigned short* W1al = W1ah + 256 * 128;
  unsigned short* W1bh = (unsigned short*)(ob + wofs + 2 * 65536);
  unsigned short* W1bl = W1bh + 256 * 256;
  unsigned short* W2ah = (unsigned short*)(ob + wofs + 2 * 65536 + 2 * 131072);
  unsigned short* W2al = W2ah + 256 * 256;
  // packed edges + padded bucket arrays in the high region (all dead pre-final-GEMM)
  unsigned int* packed = (unsigned int*)(ob + 16 * 1024 * 1024);         // 6.4MB
  int* bucketCnt    = (int*)(ob + 24 * 1024 * 1024);  // NB*BSTRIDE ints (100KB)
  int* bucketCursor = (int*)(ob + 26 * 1024 * 1024);  // NB*BSTRIDE ints (100KB)
  int* bucketStart  = (int*)(ob + 28 * 1024 * 1024);  // NB+1 ints

  dim3 blk(256);
  dim3 gEdges((N_EDGES + 255) / 256);
  dim3 gAgg((N_NODES + 3) / 4);
  dim3 gGemm((N_NODES + 63) / 64);
  dim3 gW1((128 * 256 + 255) / 256);
  dim3 gW2((256 * 256 + 255) / 256);
  dim3 gXp((N_NODES * 128 + 255) / 256);

  // ---- bucketed CSR build + weight/x prep ----
  hipMemsetAsync(bucketCnt, 0, NB * BSTRIDE * sizeof(int), stream);
  bucketHist_k<<<dim3(512), blk, 0, stream>>>(dstp, bucketCnt, N_EDGES);
  scanB_k<<<1, dim3(1024), 0, stream>>>(bucketCnt, bucketStart, bucketCursor);
  bucketScatter_k<<<gEdges, blk, 0, stream>>>(srcp, dstp, bucketCursor, packed,
                                              N_EDGES);
  fillB_k<<<dim3(NB), blk, 0, stream>>>(bucketStart, packed, rowEnd, sortedSrc,
                                        N_NODES);
  xprep_k<<<gXp, blk, 0, stream>>>(x, xh, N_NODES * 128);
  wprep_k<<<gW1, blk, 0, stream>>>(W1a, W1ah, W1al, 128, 256);
  wprep_k<<<gW2, blk, 0, stream>>>(W1b, W1bh, W1bl, 256, 256);
  wprep_k<<<gW2, blk, 0, stream>>>(W2a, W2ah, W2al, 256, 256);

  // ---- Layer 1 ----
  agg_g16_k<128, true><<<gAgg, blk, 0, stream>>>(
      xh, x, nullptr, nullptr, eps1, rowEnd, sortedSrc, C1h, C1l, N_NODES);
  gemm_wide_k<16, true, true><<<gGemm, blk, 0, stream>>>(
      C1h, C1l, W1ah, W1al, b1a, nullptr, T1h, T1l, N_NODES, 128);
  gemm_wide_k<16, true, true><<<gGemm, blk, 0, stream>>>(
      T1h, T1l, W1bh, W1bl, b1b, nullptr, Hh, Hl, N_NODES, 256);  // h as hilo

  // ---- Layer 2 ----
  agg_g16_k<256, false><<<gAgg, blk, 0, stream>>>(
      Hh, nullptr, Hh, Hl, eps2, rowEnd, sortedSrc, C2h, C2l, N_NODES);
  gemm_wide_k<16, true, true><<<gGemm, blk, 0, stream>>>(
      C2h, C2l, W2ah, W2al, b2a, nullptr, T2h, T2l, N_NODES, 256);
  wprep_k<<<gW1, blk, 0, stream>>>(W2b, W2bh, W2bl, 256, 128);  // C2 dead now
  gemm_wide_k<8, false, false><<<gGemm, blk, 0, stream>>>(
      T2h, T2l, W2bh, W2bl, b2b, out, nullptr, nullptr, N_NODES, 256);
}